// Round 5
// baseline (923.931 us; speedup 1.0000x reference)
//
#include <hip/hip_runtime.h>

#define NNODES 100000
#define NEDGES 1600000
#define IN_CH 128
#define HID 64
#define HEADS 4
#define OUT_CH 16
#define OUT_SIZE 4
#define NEG_SLOPE 0.2f

#define NPB 128           // nodes per bucket (pow2); bucket = dst >> 7
#define NPB_SHIFT 7
#define PACK_SHIFT 20     // src < 2^20 (N = 100000); local dst in bits 20..26

// ---------------- degree (int atomics, deterministic) ----------------
__global__ void k_deg_count(const int* __restrict__ dst, int* __restrict__ deg, int E) {
    int e = blockIdx.x * blockDim.x + threadIdx.x;
    if (e < E) {
        int d = dst[e];
        if ((unsigned)d < NNODES) atomicAdd(&deg[d], 1);
    }
}

__global__ void k_deg_to_f(const int* __restrict__ deg, float* __restrict__ degf, int n) {
    int i = blockIdx.x * blockDim.x + threadIdx.x;
    if (i < n) degf[i] = (float)deg[i];
}

// ---------------- exclusive scan (3-pass) for CSR rowptr ----------------
__global__ void k_scan1(const int* __restrict__ deg, int* __restrict__ incl,
                        int* __restrict__ bsum, int n) {
    int i = blockIdx.x * 256 + threadIdx.x;
    int lane = threadIdx.x & 63;
    int w = threadIdx.x >> 6;
    int val = (i < n) ? deg[i] : 0;
    #pragma unroll
    for (int off = 1; off < 64; off <<= 1) {
        int o = __shfl_up(val, off, 64);
        if (lane >= off) val += o;
    }
    __shared__ int wsum[4];
    if (lane == 63) wsum[w] = val;
    __syncthreads();
    for (int k = 0; k < w; ++k) val += wsum[k];
    if (i < n) incl[i] = val;
    if (threadIdx.x == 255) bsum[blockIdx.x] = val;
}

__global__ void k_scan2(int* __restrict__ bsum, int nb) {
    if (blockIdx.x == 0 && threadIdx.x == 0) {
        int run = 0;
        for (int b = 0; b < nb; ++b) { int t = bsum[b]; bsum[b] = run; run += t; }
    }
}

__global__ void k_scan3(const int* __restrict__ incl, const int* __restrict__ deg,
                        const int* __restrict__ bsum, int* __restrict__ rowptr, int n, int E) {
    int i = blockIdx.x * 256 + threadIdx.x;
    if (i < n) rowptr[i] = incl[i] - deg[i] + bsum[i >> 8];
    if (i == 0) rowptr[n] = E;
}

// ---------------- bucketed CSR build (write-local) ----------------
__global__ void k_bcur_init(const int* __restrict__ rowptr, int* __restrict__ bcur, int B) {
    int b = blockIdx.x * 256 + threadIdx.x;
    if (b < B) bcur[b] = rowptr[b << NPB_SHIFT];
}

// scatter edges into their bucket's contiguous region (order within bucket arbitrary)
__global__ void k_bucket_scatter(const int* __restrict__ src, const int* __restrict__ dst,
                                 int* __restrict__ bcur, int* __restrict__ ebuf, int E) {
    int e = blockIdx.x * 256 + threadIdx.x;
    if (e < E) {
        int d = dst[e], s = src[e];
        int pos = atomicAdd(&bcur[d >> NPB_SHIFT], 1);
        ebuf[pos] = s | ((d & (NPB - 1)) << PACK_SHIFT);
    }
}

// one workgroup per bucket: regroup bucket edges into exact CSR via LDS cursors
__global__ __launch_bounds__(256) void k_csr_regroup(const int* __restrict__ ebuf,
                                 const int* __restrict__ rowptr,
                                 int* __restrict__ csr, int n) {
    __shared__ int cur[NPB];
    __shared__ int rp[NPB + 1];
    const int base = blockIdx.x << NPB_SHIFT;
    const int t = threadIdx.x;
    for (int i = t; i <= NPB; i += 256) {
        int node = base + i;
        rp[i] = rowptr[node <= n ? node : n];
    }
    for (int i = t; i < NPB; i += 256) cur[i] = 0;
    __syncthreads();
    const int beg = rp[0], end = rp[NPB];
    for (int j = beg + t; j < end; j += 256) {
        int w = ebuf[j];
        int local = w >> PACK_SHIFT;
        int pos = atomicAdd(&cur[local], 1);
        csr[rp[local] + pos] = w & ((1 << PACK_SHIFT) - 1);
    }
}

// ---------------- tiled GEMM + fused bias + attention scores ----------------
template<int IN>
__global__ __launch_bounds__(256) void k_linear_t(const float* __restrict__ x,
                         const float* __restrict__ W, const float* __restrict__ bias,
                         const float* __restrict__ att,
                         float* __restrict__ h, float* __restrict__ si, float* __restrict__ sj,
                         int n) {
    constexpr int BM = 64, BN = 64, BK = 32;
    constexpr int LDA = BM + 4;
    constexpr int LDB = BN + 4;
    constexpr int LDH = BN + 4;
    __shared__ float As[BK][LDA];
    __shared__ float Bs[BK][LDB];
    __shared__ float hs[BM][LDH];

    const int tid = threadIdx.x;
    const int node0 = blockIdx.x * BM;
    const int tn = (tid & 15) * 4;
    const int tm = (tid >> 4) * 4;

    float acc[4][4] = {};

    for (int kk = 0; kk < IN; kk += BK) {
        #pragma unroll
        for (int i = 0; i < 2; ++i) {
            int idx = tid * 2 + i;
            int m   = idx >> 3;
            int c4  = (idx & 7) * 4;
            int g = node0 + m;
            float4 v = make_float4(0.f, 0.f, 0.f, 0.f);
            if (g < n) v = *reinterpret_cast<const float4*>(&x[(size_t)g * IN + kk + c4]);
            As[c4 + 0][m] = v.x; As[c4 + 1][m] = v.y;
            As[c4 + 2][m] = v.z; As[c4 + 3][m] = v.w;
            float4 w = *reinterpret_cast<const float4*>(&W[(size_t)m * IN + kk + c4]);
            Bs[c4 + 0][m] = w.x; Bs[c4 + 1][m] = w.y;
            Bs[c4 + 2][m] = w.z; Bs[c4 + 3][m] = w.w;
        }
        __syncthreads();
        #pragma unroll
        for (int k = 0; k < BK; ++k) {
            float4 a = *reinterpret_cast<const float4*>(&As[k][tm]);
            float4 b = *reinterpret_cast<const float4*>(&Bs[k][tn]);
            acc[0][0] = fmaf(a.x, b.x, acc[0][0]); acc[0][1] = fmaf(a.x, b.y, acc[0][1]);
            acc[0][2] = fmaf(a.x, b.z, acc[0][2]); acc[0][3] = fmaf(a.x, b.w, acc[0][3]);
            acc[1][0] = fmaf(a.y, b.x, acc[1][0]); acc[1][1] = fmaf(a.y, b.y, acc[1][1]);
            acc[1][2] = fmaf(a.y, b.z, acc[1][2]); acc[1][3] = fmaf(a.y, b.w, acc[1][3]);
            acc[2][0] = fmaf(a.z, b.x, acc[2][0]); acc[2][1] = fmaf(a.z, b.y, acc[2][1]);
            acc[2][2] = fmaf(a.z, b.z, acc[2][2]); acc[2][3] = fmaf(a.z, b.w, acc[2][3]);
            acc[3][0] = fmaf(a.w, b.x, acc[3][0]); acc[3][1] = fmaf(a.w, b.y, acc[3][1]);
            acc[3][2] = fmaf(a.w, b.z, acc[3][2]); acc[3][3] = fmaf(a.w, b.w, acc[3][3]);
        }
        __syncthreads();
    }

    float4 bv = *reinterpret_cast<const float4*>(&bias[tn]);
    #pragma unroll
    for (int i = 0; i < 4; ++i) {
        float4 v = make_float4(acc[i][0] + bv.x, acc[i][1] + bv.y,
                               acc[i][2] + bv.z, acc[i][3] + bv.w);
        *reinterpret_cast<float4*>(&hs[tm + i][tn]) = v;
        int g = node0 + tm + i;
        if (g < n) *reinterpret_cast<float4*>(&h[(size_t)g * HID + tn]) = v;
    }
    __syncthreads();

    int nodel = tid >> 2, head = tid & 3;
    int g = node0 + nodel;
    if (g < n) {
        const float* arow = att + head * (2 * OUT_CH);
        const float* hrow = &hs[nodel][head * OUT_CH];
        float vi = 0.f, vj = 0.f;
        #pragma unroll
        for (int c = 0; c < OUT_CH; ++c) {
            float hv = hrow[c];
            vi = fmaf(hv, arow[c], vi);
            vj = fmaf(hv, arow[OUT_CH + c], vj);
        }
        si[g * HEADS + head] = vi;
        sj[g * HEADS + head] = vj;
    }
}

// ---------------- CSR gather aggregation (no atomics) ----------------
// 4 nodes per wave (16 lanes each, float4 per lane); unroll 2 -> 8 loads in flight.
__global__ __launch_bounds__(256) void k_gather(const int* __restrict__ csr_src,
                        const int* __restrict__ rowptr,
                        const float* __restrict__ h, const float* __restrict__ si,
                        const float* __restrict__ sj, const float* __restrict__ degf,
                        float* __restrict__ out, int n) {
    const int wid  = threadIdx.x >> 6;
    const int lane = threadIdx.x & 63;
    const int l16  = lane & 15;
    const int head = l16 >> 2;
    const int node = blockIdx.x * 16 + wid * 4 + (lane >> 4);
    const bool active = node < n;

    int beg = 0, end = 0;
    float sid = 0.f, invd = 0.f;
    if (active) {
        beg = rowptr[node];
        end = rowptr[node + 1];
        sid = si[node * HEADS + head];
        if (end > beg) invd = 1.0f / degf[node];
    }

    float4 acc = make_float4(0.f, 0.f, 0.f, 0.f);
    int j = beg;
    while (__any(j < end)) {
        bool p0 = j < end;
        bool p1 = j + 1 < end;
        int j0 = p0 ? j : 0;
        int j1 = p1 ? j + 1 : 0;
        int s0 = csr_src[j0];
        int s1 = csr_src[j1];
        float e0 = sj[s0 * HEADS + head];
        float e1 = sj[s1 * HEADS + head];
        float4 h0 = *reinterpret_cast<const float4*>(&h[(size_t)s0 * HID + (l16 << 2)]);
        float4 h1 = *reinterpret_cast<const float4*>(&h[(size_t)s1 * HID + (l16 << 2)]);
        float a0 = sid + e0; a0 = (a0 > 0.f) ? a0 : a0 * NEG_SLOPE; a0 = p0 ? a0 : 0.f;
        float a1 = sid + e1; a1 = (a1 > 0.f) ? a1 : a1 * NEG_SLOPE; a1 = p1 ? a1 : 0.f;
        acc.x = fmaf(h0.x, a0, acc.x); acc.y = fmaf(h0.y, a0, acc.y);
        acc.z = fmaf(h0.z, a0, acc.z); acc.w = fmaf(h0.w, a0, acc.w);
        acc.x = fmaf(h1.x, a1, acc.x); acc.y = fmaf(h1.y, a1, acc.y);
        acc.z = fmaf(h1.z, a1, acc.z); acc.w = fmaf(h1.w, a1, acc.w);
        j += 2;
    }
    if (active) {
        acc.x *= invd; acc.y *= invd; acc.z *= invd; acc.w *= invd;
        *reinterpret_cast<float4*>(&out[(size_t)node * HID + (l16 << 2)]) = acc;
    }
}

// ---------------- final fc ----------------
__global__ void k_fc(const float* __restrict__ x, const float* __restrict__ fcW,
                     const float* __restrict__ fcb, float* __restrict__ out, int n) {
    int i = blockIdx.x * blockDim.x + threadIdx.x;
    if (i >= n * OUT_SIZE) return;
    int node = i >> 2, o = i & 3;
    const float* xr = x + (size_t)node * HID;
    const float* wr = fcW + o * HID;
    float acc = fcb[o];
    #pragma unroll
    for (int k = 0; k < HID; ++k) acc = fmaf(xr[k], wr[k], acc);
    out[i] = acc;
}

extern "C" void kernel_launch(void* const* d_in, const int* in_sizes, int n_in,
                              void* d_out, int out_size, void* d_ws, size_t ws_size,
                              hipStream_t stream) {
    const float* x0   = (const float*)d_in[0];
    const int*   ei   = (const int*)d_in[1];
    const int E = in_sizes[1] / 2;
    const int N = in_sizes[0] / IN_CH;
    const int* srcp = ei;        // edge_index[0] = x_j (source)
    const int* dstp = ei + E;    // edge_index[1] = x_i (aggregation target)

    const float* W[4] = {(const float*)d_in[2], (const float*)d_in[5], (const float*)d_in[8],  (const float*)d_in[11]};
    const float* B[4] = {(const float*)d_in[3], (const float*)d_in[6], (const float*)d_in[9],  (const float*)d_in[12]};
    const float* A[4] = {(const float*)d_in[4], (const float*)d_in[7], (const float*)d_in[10], (const float*)d_in[13]};
    const float* fcW = (const float*)d_in[14];
    const float* fcb = (const float*)d_in[15];

    // workspace layout
    float* ws    = (float*)d_ws;
    float* hbuf  = ws;                        // N*64  (aliased as ebuf during CSR build)
    float* xa    = hbuf + (size_t)N * HID;    // N*64
    float* si    = xa   + (size_t)N * HID;    // N*4
    float* sj    = si   + (size_t)N * HEADS;  // N*4
    float* degf  = sj   + (size_t)N * HEADS;  // N
    int*   degi  = (int*)(degf + N);          // N
    int*   rowptr= degi + N;                  // N+1
    int*   incl  = rowptr + N + 1;            // N
    int*   bsum  = incl + N;                  // 1024
    int*   bcur  = bsum + 1024;               // num buckets (<= N)
    int*   csr   = bcur + N;                  // E
    int*   ebuf  = (int*)hbuf;                // E ints, consumed before layer 0 writes hbuf

    const int nb = (N + 255) / 256;
    const int nbk = (N + NPB - 1) / NPB;      // buckets
    hipMemsetAsync(degi, 0, (size_t)N * sizeof(int), stream);
    k_deg_count<<<(E + 255) / 256, 256, 0, stream>>>(dstp, degi, E);
    k_deg_to_f<<<nb, 256, 0, stream>>>(degi, degf, N);
    k_scan1<<<nb, 256, 0, stream>>>(degi, incl, bsum, N);
    k_scan2<<<1, 64, 0, stream>>>(bsum, nb);
    k_scan3<<<nb, 256, 0, stream>>>(incl, degi, bsum, rowptr, N, E);
    k_bcur_init<<<(nbk + 255) / 256, 256, 0, stream>>>(rowptr, bcur, nbk);
    k_bucket_scatter<<<(E + 255) / 256, 256, 0, stream>>>(srcp, dstp, bcur, ebuf, E);
    k_csr_regroup<<<nbk, 256, 0, stream>>>(ebuf, rowptr, csr, N);

    const int nblk = (N + 63) / 64;
    const int gblk = (N + 15) / 16;
    const float* cur = x0;
    for (int l = 0; l < 4; ++l) {
        if (l == 0)
            k_linear_t<IN_CH><<<nblk, 256, 0, stream>>>(cur, W[l], B[l], A[l], hbuf, si, sj, N);
        else
            k_linear_t<HID><<<nblk, 256, 0, stream>>>(cur, W[l], B[l], A[l], hbuf, si, sj, N);
        float* ob = (l == 0) ? xa : (float*)cur;   // in-place from layer 1 on
        k_gather<<<gblk, 256, 0, stream>>>(csr, rowptr, hbuf, si, sj, degf, ob, N);
        cur = ob;
    }
    k_fc<<<(N * OUT_SIZE + 255) / 256, 256, 0, stream>>>(cur, fcW, fcb, (float*)d_out, N);
}

// Round 6
// 597.542 us; speedup vs baseline: 1.5462x; 1.5462x over previous
//
#include <hip/hip_runtime.h>

#define NNODES 100000
#define NEDGES 1600000
#define IN_CH 128
#define HID 64
#define HEADS 4
#define OUT_CH 16
#define OUT_SIZE 4
#define NEG_SLOPE 0.2f

// ---------------- degree (int atomics over 100k addrs: low contention) ----------------
__global__ void k_deg_count(const int* __restrict__ dst, int* __restrict__ deg, int E) {
    int e = blockIdx.x * blockDim.x + threadIdx.x;
    if (e < E) {
        int d = dst[e];
        if ((unsigned)d < NNODES) atomicAdd(&deg[d], 1);
    }
}

// ---------------- exclusive scan (3-pass) for CSR rowptr ----------------
__global__ void k_scan1(const int* __restrict__ deg, int* __restrict__ incl,
                        int* __restrict__ bsum, int n) {
    int i = blockIdx.x * 256 + threadIdx.x;
    int lane = threadIdx.x & 63;
    int w = threadIdx.x >> 6;
    int val = (i < n) ? deg[i] : 0;
    #pragma unroll
    for (int off = 1; off < 64; off <<= 1) {
        int o = __shfl_up(val, off, 64);
        if (lane >= off) val += o;
    }
    __shared__ int wsum[4];
    if (lane == 63) wsum[w] = val;
    __syncthreads();
    for (int k = 0; k < w; ++k) val += wsum[k];
    if (i < n) incl[i] = val;
    if (threadIdx.x == 255) bsum[blockIdx.x] = val;
}

__global__ void k_scan2(int* __restrict__ bsum, int nb) {
    if (blockIdx.x == 0 && threadIdx.x == 0) {
        int run = 0;
        for (int b = 0; b < nb; ++b) { int t = bsum[b]; bsum[b] = run; run += t; }
    }
}

__global__ void k_scan3(const int* __restrict__ incl, const int* __restrict__ deg,
                        const int* __restrict__ bsum, int* __restrict__ rowptr,
                        float* __restrict__ degf, int n, int E) {
    int i = blockIdx.x * 256 + threadIdx.x;
    if (i < n) {
        rowptr[i] = incl[i] - deg[i] + bsum[i >> 8];
        degf[i] = (float)deg[i];
    }
    if (i == 0) rowptr[n] = E;
}

// per-node atomic cursor (100k addresses -> negligible contention)
__global__ void k_csr_fill(const int* __restrict__ src, const int* __restrict__ dst,
                           const int* __restrict__ rowptr, int* __restrict__ cursor,
                           int* __restrict__ csr_src, int E) {
    int e = blockIdx.x * 256 + threadIdx.x;
    if (e < E) {
        int d = dst[e];
        int pos = atomicAdd(&cursor[d], 1);
        csr_src[rowptr[d] + pos] = src[e];
    }
}

// ---------------- tiled GEMM + fused bias + attention scores ----------------
// BM=BN=64, BK=32, 256 thr, 4x4 micro-tile. si/sj via in-register 4-lane shuffle
// reduction (no hs LDS tile): LDS = 17.4 KB -> ~8 blocks/CU.
template<int IN>
__global__ __launch_bounds__(256) void k_linear_t(const float* __restrict__ x,
                         const float* __restrict__ W, const float* __restrict__ bias,
                         const float* __restrict__ att,
                         float* __restrict__ h, float* __restrict__ si, float* __restrict__ sj,
                         int n) {
    constexpr int BM = 64, BK = 32;
    constexpr int LD = BM + 4;
    __shared__ float As[BK][LD];
    __shared__ float Bs[BK][LD];

    const int tid = threadIdx.x;
    const int node0 = blockIdx.x * BM;
    const int v = tid & 15;
    const int tn = v * 4;            // output channel base
    const int tm = (tid >> 4) * 4;   // node-row base

    float acc[4][4] = {};

    for (int kk = 0; kk < IN; kk += BK) {
        #pragma unroll
        for (int i = 0; i < 2; ++i) {
            int idx = tid * 2 + i;
            int m   = idx >> 3;
            int c4  = (idx & 7) * 4;
            int g = node0 + m;
            float4 vx = make_float4(0.f, 0.f, 0.f, 0.f);
            if (g < n) vx = *reinterpret_cast<const float4*>(&x[(size_t)g * IN + kk + c4]);
            As[c4 + 0][m] = vx.x; As[c4 + 1][m] = vx.y;
            As[c4 + 2][m] = vx.z; As[c4 + 3][m] = vx.w;
            float4 w = *reinterpret_cast<const float4*>(&W[(size_t)m * IN + kk + c4]);
            Bs[c4 + 0][m] = w.x; Bs[c4 + 1][m] = w.y;
            Bs[c4 + 2][m] = w.z; Bs[c4 + 3][m] = w.w;
        }
        __syncthreads();
        #pragma unroll
        for (int k = 0; k < BK; ++k) {
            float4 a = *reinterpret_cast<const float4*>(&As[k][tm]);
            float4 b = *reinterpret_cast<const float4*>(&Bs[k][tn]);
            acc[0][0] = fmaf(a.x, b.x, acc[0][0]); acc[0][1] = fmaf(a.x, b.y, acc[0][1]);
            acc[0][2] = fmaf(a.x, b.z, acc[0][2]); acc[0][3] = fmaf(a.x, b.w, acc[0][3]);
            acc[1][0] = fmaf(a.y, b.x, acc[1][0]); acc[1][1] = fmaf(a.y, b.y, acc[1][1]);
            acc[1][2] = fmaf(a.y, b.z, acc[1][2]); acc[1][3] = fmaf(a.y, b.w, acc[1][3]);
            acc[2][0] = fmaf(a.z, b.x, acc[2][0]); acc[2][1] = fmaf(a.z, b.y, acc[2][1]);
            acc[2][2] = fmaf(a.z, b.z, acc[2][2]); acc[2][3] = fmaf(a.z, b.w, acc[2][3]);
            acc[3][0] = fmaf(a.w, b.x, acc[3][0]); acc[3][1] = fmaf(a.w, b.y, acc[3][1]);
            acc[3][2] = fmaf(a.w, b.z, acc[3][2]); acc[3][3] = fmaf(a.w, b.w, acc[3][3]);
        }
        __syncthreads();
    }

    // bias into acc (h includes bias; si/sj are computed from biased h)
    float4 bv = *reinterpret_cast<const float4*>(&bias[tn]);
    #pragma unroll
    for (int r = 0; r < 4; ++r) {
        acc[r][0] += bv.x; acc[r][1] += bv.y; acc[r][2] += bv.z; acc[r][3] += bv.w;
    }
    // h store
    #pragma unroll
    for (int r = 0; r < 4; ++r) {
        int g = node0 + tm + r;
        if (g < n)
            *reinterpret_cast<float4*>(&h[(size_t)g * HID + tn]) =
                make_float4(acc[r][0], acc[r][1], acc[r][2], acc[r][3]);
    }

    // attention scores: aligned 4-lane group (v&~3 .. +3) covers head (v>>2)'s 16 cols
    const int head = v >> 2;
    const int cl = (v & 3) * 4;   // local col within head
    const float* arow = att + head * (2 * OUT_CH);
    float pi[4], pj[4];
    #pragma unroll
    for (int r = 0; r < 4; ++r) {
        float vi = 0.f, vj = 0.f;
        #pragma unroll
        for (int c = 0; c < 4; ++c) {
            vi = fmaf(acc[r][c], arow[cl + c], vi);
            vj = fmaf(acc[r][c], arow[OUT_CH + cl + c], vj);
        }
        pi[r] = vi; pj[r] = vj;
    }
    #pragma unroll
    for (int r = 0; r < 4; ++r) {
        pi[r] += __shfl_xor(pi[r], 1); pi[r] += __shfl_xor(pi[r], 2);
        pj[r] += __shfl_xor(pj[r], 1); pj[r] += __shfl_xor(pj[r], 2);
    }
    int r = v & 3;
    int g = node0 + tm + r;
    if (g < n) {
        si[g * HEADS + head] = pi[r];
        sj[g * HEADS + head] = pj[r];
    }
}

// ---------------- CSR gather aggregation (no atomics) ----------------
// 4 nodes per wave (16 lanes each, float4 per lane); unroll 4 -> 16 gather
// streams in flight per wave.
__global__ __launch_bounds__(256) void k_gather(const int* __restrict__ csr_src,
                        const int* __restrict__ rowptr,
                        const float* __restrict__ h, const float* __restrict__ si,
                        const float* __restrict__ sj, const float* __restrict__ degf,
                        float* __restrict__ out, int n) {
    const int wid  = threadIdx.x >> 6;
    const int lane = threadIdx.x & 63;
    const int l16  = lane & 15;
    const int head = l16 >> 2;
    const int node = blockIdx.x * 16 + wid * 4 + (lane >> 4);
    const bool active = node < n;

    int beg = 0, end = 0;
    float sid = 0.f, invd = 0.f;
    if (active) {
        beg = rowptr[node];
        end = rowptr[node + 1];
        sid = si[node * HEADS + head];
        if (end > beg) invd = 1.0f / degf[node];
    }

    float4 acc = make_float4(0.f, 0.f, 0.f, 0.f);
    int j = beg;
    while (__any(j < end)) {
        float a[4];
        float4 hv[4];
        #pragma unroll
        for (int u = 0; u < 4; ++u) {
            bool p = (j + u) < end;
            int jj = p ? j + u : 0;
            int s = csr_src[jj];
            float e = sj[s * HEADS + head];
            hv[u] = *reinterpret_cast<const float4*>(&h[(size_t)s * HID + (l16 << 2)]);
            float av = sid + e;
            av = (av > 0.f) ? av : av * NEG_SLOPE;
            a[u] = p ? av : 0.f;
        }
        #pragma unroll
        for (int u = 0; u < 4; ++u) {
            acc.x = fmaf(hv[u].x, a[u], acc.x);
            acc.y = fmaf(hv[u].y, a[u], acc.y);
            acc.z = fmaf(hv[u].z, a[u], acc.z);
            acc.w = fmaf(hv[u].w, a[u], acc.w);
        }
        j += 4;
    }
    if (active) {
        acc.x *= invd; acc.y *= invd; acc.z *= invd; acc.w *= invd;
        *reinterpret_cast<float4*>(&out[(size_t)node * HID + (l16 << 2)]) = acc;
    }
}

// ---------------- final fc ----------------
__global__ void k_fc(const float* __restrict__ x, const float* __restrict__ fcW,
                     const float* __restrict__ fcb, float* __restrict__ out, int n) {
    int i = blockIdx.x * blockDim.x + threadIdx.x;
    if (i >= n * OUT_SIZE) return;
    int node = i >> 2, o = i & 3;
    const float* xr = x + (size_t)node * HID;
    const float* wr = fcW + o * HID;
    float acc = fcb[o];
    #pragma unroll
    for (int k = 0; k < HID; ++k) acc = fmaf(xr[k], wr[k], acc);
    out[i] = acc;
}

extern "C" void kernel_launch(void* const* d_in, const int* in_sizes, int n_in,
                              void* d_out, int out_size, void* d_ws, size_t ws_size,
                              hipStream_t stream) {
    const float* x0   = (const float*)d_in[0];
    const int*   ei   = (const int*)d_in[1];
    const int E = in_sizes[1] / 2;
    const int N = in_sizes[0] / IN_CH;
    const int* srcp = ei;        // edge_index[0] = x_j (source)
    const int* dstp = ei + E;    // edge_index[1] = x_i (aggregation target)

    const float* W[4] = {(const float*)d_in[2], (const float*)d_in[5], (const float*)d_in[8],  (const float*)d_in[11]};
    const float* B[4] = {(const float*)d_in[3], (const float*)d_in[6], (const float*)d_in[9],  (const float*)d_in[12]};
    const float* A[4] = {(const float*)d_in[4], (const float*)d_in[7], (const float*)d_in[10], (const float*)d_in[13]};
    const float* fcW = (const float*)d_in[14];
    const float* fcb = (const float*)d_in[15];

    // workspace layout
    float* ws    = (float*)d_ws;
    float* hbuf  = ws;                        // N*64
    float* xa    = hbuf + (size_t)N * HID;    // N*64
    float* si    = xa   + (size_t)N * HID;    // N*4
    float* sj    = si   + (size_t)N * HEADS;  // N*4
    float* degf  = sj   + (size_t)N * HEADS;  // N
    int*   degi  = (int*)(degf + N);          // N
    int*   rowptr= degi + N;                  // N+1
    int*   incl  = rowptr + N + 1;            // N
    int*   bsum  = incl + N;                  // 1024
    int*   cursor= bsum + 1024;               // N
    int*   csr   = cursor + N;                // E

    const int nb = (N + 255) / 256;
    hipMemsetAsync(degi, 0, (size_t)N * sizeof(int), stream);
    hipMemsetAsync(cursor, 0, (size_t)N * sizeof(int), stream);
    k_deg_count<<<(E + 255) / 256, 256, 0, stream>>>(dstp, degi, E);
    k_scan1<<<nb, 256, 0, stream>>>(degi, incl, bsum, N);
    k_scan2<<<1, 64, 0, stream>>>(bsum, nb);
    k_scan3<<<nb, 256, 0, stream>>>(incl, degi, bsum, rowptr, degf, N, E);
    k_csr_fill<<<(E + 255) / 256, 256, 0, stream>>>(srcp, dstp, rowptr, cursor, csr, E);

    const int nblk = (N + 63) / 64;
    const int gblk = (N + 15) / 16;
    const float* cur = x0;
    for (int l = 0; l < 4; ++l) {
        if (l == 0)
            k_linear_t<IN_CH><<<nblk, 256, 0, stream>>>(cur, W[l], B[l], A[l], hbuf, si, sj, N);
        else
            k_linear_t<HID><<<nblk, 256, 0, stream>>>(cur, W[l], B[l], A[l], hbuf, si, sj, N);
        float* ob = (l == 0) ? xa : (float*)cur;   // in-place from layer 1 on
        k_gather<<<gblk, 256, 0, stream>>>(csr, rowptr, hbuf, si, sj, degf, ob, N);
        cur = ob;
    }
    k_fc<<<(N * OUT_SIZE + 255) / 256, 256, 0, stream>>>(cur, fcW, fcb, (float*)d_out, N);
}

// Round 7
// 568.156 us; speedup vs baseline: 1.6262x; 1.0517x over previous
//
#include <hip/hip_runtime.h>

#define NNODES 100000
#define NEDGES 1600000
#define IN_CH 128
#define HID 64
#define HEADS 4
#define OUT_CH 16
#define OUT_SIZE 4
#define NEG_SLOPE 0.2f
#define NXCD 8

// ---------------- degree (int atomics over 100k addrs: low contention) ----------------
__global__ void k_deg_count(const int* __restrict__ dst, int* __restrict__ deg, int E) {
    int e = blockIdx.x * blockDim.x + threadIdx.x;
    if (e < E) {
        int d = dst[e];
        if ((unsigned)d < NNODES) atomicAdd(&deg[d], 1);
    }
}

// ---------------- exclusive scan (3-pass) for CSR rowptr ----------------
__global__ void k_scan1(const int* __restrict__ deg, int* __restrict__ incl,
                        int* __restrict__ bsum, int n) {
    int i = blockIdx.x * 256 + threadIdx.x;
    int lane = threadIdx.x & 63;
    int w = threadIdx.x >> 6;
    int val = (i < n) ? deg[i] : 0;
    #pragma unroll
    for (int off = 1; off < 64; off <<= 1) {
        int o = __shfl_up(val, off, 64);
        if (lane >= off) val += o;
    }
    __shared__ int wsum[4];
    if (lane == 63) wsum[w] = val;
    __syncthreads();
    for (int k = 0; k < w; ++k) val += wsum[k];
    if (i < n) incl[i] = val;
    if (threadIdx.x == 255) bsum[blockIdx.x] = val;
}

__global__ void k_scan2(int* __restrict__ bsum, int nb) {
    if (blockIdx.x == 0 && threadIdx.x == 0) {
        int run = 0;
        for (int b = 0; b < nb; ++b) { int t = bsum[b]; bsum[b] = run; run += t; }
    }
}

__global__ void k_scan3(const int* __restrict__ incl, const int* __restrict__ deg,
                        const int* __restrict__ bsum, int* __restrict__ rowptr,
                        float* __restrict__ degf, int* __restrict__ cursor, int n, int E) {
    int i = blockIdx.x * 256 + threadIdx.x;
    if (i < n) {
        rowptr[i] = incl[i] - deg[i] + bsum[i >> 8];
        degf[i] = (float)deg[i];
        cursor[i] = 0;
    }
    if (i == 0) rowptr[n] = E;
}

// ---------------- XCD-partitioned CSR fill ----------------
// blockIdx & 7 selects a dst-range; default dispatch round-robins blocks over
// the 8 XCDs, so each range's csr sub-region (~800 KB) is written from one
// XCD's L2 -> lines fill before writeback. Correctness is mapping-independent
// (chunk x range tiles partition the edge set exactly).
__global__ __launch_bounds__(256) void k_csr_fill_part(const int* __restrict__ src,
                           const int* __restrict__ dst,
                           const int* __restrict__ rowptr, int* __restrict__ cursor,
                           int* __restrict__ csr_src, int E, int rng) {
    const int range = blockIdx.x & (NXCD - 1);
    const int chunk = blockIdx.x >> 3;
    const int lo = range * rng, hi = lo + rng;
    const int base = chunk * 2048 + threadIdx.x;
    #pragma unroll
    for (int i = 0; i < 8; ++i) {
        int e = base + i * 256;
        if (e < E) {
            int d = dst[e];
            if (d >= lo && d < hi) {
                int pos = atomicAdd(&cursor[d], 1);
                csr_src[rowptr[d] + pos] = src[e];
            }
        }
    }
}

// ---------------- tiled GEMM + fused bias + attention scores ----------------
// BM=BN=64, BK=32, 256 thr, 4x4 micro-tile. si/sj via in-register 4-lane shuffle
// reduction (no hs LDS tile): LDS = 17.4 KB.
template<int IN>
__global__ __launch_bounds__(256) void k_linear_t(const float* __restrict__ x,
                         const float* __restrict__ W, const float* __restrict__ bias,
                         const float* __restrict__ att,
                         float* __restrict__ h, float* __restrict__ si, float* __restrict__ sj,
                         int n) {
    constexpr int BM = 64, BK = 32;
    constexpr int LD = BM + 4;
    __shared__ float As[BK][LD];
    __shared__ float Bs[BK][LD];

    const int tid = threadIdx.x;
    const int node0 = blockIdx.x * BM;
    const int v = tid & 15;
    const int tn = v * 4;            // output channel base
    const int tm = (tid >> 4) * 4;   // node-row base

    float acc[4][4] = {};

    for (int kk = 0; kk < IN; kk += BK) {
        #pragma unroll
        for (int i = 0; i < 2; ++i) {
            int idx = tid * 2 + i;
            int m   = idx >> 3;
            int c4  = (idx & 7) * 4;
            int g = node0 + m;
            float4 vx = make_float4(0.f, 0.f, 0.f, 0.f);
            if (g < n) vx = *reinterpret_cast<const float4*>(&x[(size_t)g * IN + kk + c4]);
            As[c4 + 0][m] = vx.x; As[c4 + 1][m] = vx.y;
            As[c4 + 2][m] = vx.z; As[c4 + 3][m] = vx.w;
            float4 w = *reinterpret_cast<const float4*>(&W[(size_t)m * IN + kk + c4]);
            Bs[c4 + 0][m] = w.x; Bs[c4 + 1][m] = w.y;
            Bs[c4 + 2][m] = w.z; Bs[c4 + 3][m] = w.w;
        }
        __syncthreads();
        #pragma unroll
        for (int k = 0; k < BK; ++k) {
            float4 a = *reinterpret_cast<const float4*>(&As[k][tm]);
            float4 b = *reinterpret_cast<const float4*>(&Bs[k][tn]);
            acc[0][0] = fmaf(a.x, b.x, acc[0][0]); acc[0][1] = fmaf(a.x, b.y, acc[0][1]);
            acc[0][2] = fmaf(a.x, b.z, acc[0][2]); acc[0][3] = fmaf(a.x, b.w, acc[0][3]);
            acc[1][0] = fmaf(a.y, b.x, acc[1][0]); acc[1][1] = fmaf(a.y, b.y, acc[1][1]);
            acc[1][2] = fmaf(a.y, b.z, acc[1][2]); acc[1][3] = fmaf(a.y, b.w, acc[1][3]);
            acc[2][0] = fmaf(a.z, b.x, acc[2][0]); acc[2][1] = fmaf(a.z, b.y, acc[2][1]);
            acc[2][2] = fmaf(a.z, b.z, acc[2][2]); acc[2][3] = fmaf(a.z, b.w, acc[2][3]);
            acc[3][0] = fmaf(a.w, b.x, acc[3][0]); acc[3][1] = fmaf(a.w, b.y, acc[3][1]);
            acc[3][2] = fmaf(a.w, b.z, acc[3][2]); acc[3][3] = fmaf(a.w, b.w, acc[3][3]);
        }
        __syncthreads();
    }

    float4 bv = *reinterpret_cast<const float4*>(&bias[tn]);
    #pragma unroll
    for (int r = 0; r < 4; ++r) {
        acc[r][0] += bv.x; acc[r][1] += bv.y; acc[r][2] += bv.z; acc[r][3] += bv.w;
    }
    #pragma unroll
    for (int r = 0; r < 4; ++r) {
        int g = node0 + tm + r;
        if (g < n)
            *reinterpret_cast<float4*>(&h[(size_t)g * HID + tn]) =
                make_float4(acc[r][0], acc[r][1], acc[r][2], acc[r][3]);
    }

    // attention scores: aligned 4-lane group covers head (v>>2)'s 16 cols
    const int head = v >> 2;
    const int cl = (v & 3) * 4;
    const float* arow = att + head * (2 * OUT_CH);
    float pi[4], pj[4];
    #pragma unroll
    for (int r = 0; r < 4; ++r) {
        float vi = 0.f, vj = 0.f;
        #pragma unroll
        for (int c = 0; c < 4; ++c) {
            vi = fmaf(acc[r][c], arow[cl + c], vi);
            vj = fmaf(acc[r][c], arow[OUT_CH + cl + c], vj);
        }
        pi[r] = vi; pj[r] = vj;
    }
    #pragma unroll
    for (int r = 0; r < 4; ++r) {
        pi[r] += __shfl_xor(pi[r], 1); pi[r] += __shfl_xor(pi[r], 2);
        pj[r] += __shfl_xor(pj[r], 1); pj[r] += __shfl_xor(pj[r], 2);
    }
    int r = v & 3;
    int g = node0 + tm + r;
    if (g < n) {
        si[g * HEADS + head] = pi[r];
        sj[g * HEADS + head] = pj[r];
    }
}

// ---------------- CSR gather aggregation (no atomics) ----------------
// 4 nodes per wave (16 lanes each, float4 per lane); unroll 8 -> 32 gather
// streams in flight per wave. Masked slots re-load index 0 (L1-resident).
__global__ __launch_bounds__(256) void k_gather(const int* __restrict__ csr_src,
                        const int* __restrict__ rowptr,
                        const float* __restrict__ h, const float* __restrict__ si,
                        const float* __restrict__ sj, const float* __restrict__ degf,
                        float* __restrict__ out, int n) {
    const int wid  = threadIdx.x >> 6;
    const int lane = threadIdx.x & 63;
    const int l16  = lane & 15;
    const int head = l16 >> 2;
    const int node = blockIdx.x * 16 + wid * 4 + (lane >> 4);
    const bool active = node < n;

    int beg = 0, end = 0;
    float sid = 0.f, invd = 0.f;
    if (active) {
        beg = rowptr[node];
        end = rowptr[node + 1];
        sid = si[node * HEADS + head];
        if (end > beg) invd = 1.0f / degf[node];
    }

    float4 acc = make_float4(0.f, 0.f, 0.f, 0.f);
    int j = beg;
    while (__any(j < end)) {
        float a[8];
        float4 hv[8];
        #pragma unroll
        for (int u = 0; u < 8; ++u) {
            bool p = (j + u) < end;
            int jj = p ? j + u : 0;
            int s = csr_src[jj];
            float e = sj[s * HEADS + head];
            hv[u] = *reinterpret_cast<const float4*>(&h[(size_t)s * HID + (l16 << 2)]);
            float av = sid + e;
            av = (av > 0.f) ? av : av * NEG_SLOPE;
            a[u] = p ? av : 0.f;
        }
        #pragma unroll
        for (int u = 0; u < 8; ++u) {
            acc.x = fmaf(hv[u].x, a[u], acc.x);
            acc.y = fmaf(hv[u].y, a[u], acc.y);
            acc.z = fmaf(hv[u].z, a[u], acc.z);
            acc.w = fmaf(hv[u].w, a[u], acc.w);
        }
        j += 8;
    }
    if (active) {
        acc.x *= invd; acc.y *= invd; acc.z *= invd; acc.w *= invd;
        *reinterpret_cast<float4*>(&out[(size_t)node * HID + (l16 << 2)]) = acc;
    }
}

// ---------------- final fc ----------------
__global__ void k_fc(const float* __restrict__ x, const float* __restrict__ fcW,
                     const float* __restrict__ fcb, float* __restrict__ out, int n) {
    int i = blockIdx.x * blockDim.x + threadIdx.x;
    if (i >= n * OUT_SIZE) return;
    int node = i >> 2, o = i & 3;
    const float* xr = x + (size_t)node * HID;
    const float* wr = fcW + o * HID;
    float acc = fcb[o];
    #pragma unroll
    for (int k = 0; k < HID; ++k) acc = fmaf(xr[k], wr[k], acc);
    out[i] = acc;
}

extern "C" void kernel_launch(void* const* d_in, const int* in_sizes, int n_in,
                              void* d_out, int out_size, void* d_ws, size_t ws_size,
                              hipStream_t stream) {
    const float* x0   = (const float*)d_in[0];
    const int*   ei   = (const int*)d_in[1];
    const int E = in_sizes[1] / 2;
    const int N = in_sizes[0] / IN_CH;
    const int* srcp = ei;        // edge_index[0] = x_j (source)
    const int* dstp = ei + E;    // edge_index[1] = x_i (aggregation target)

    const float* W[4] = {(const float*)d_in[2], (const float*)d_in[5], (const float*)d_in[8],  (const float*)d_in[11]};
    const float* B[4] = {(const float*)d_in[3], (const float*)d_in[6], (const float*)d_in[9],  (const float*)d_in[12]};
    const float* A[4] = {(const float*)d_in[4], (const float*)d_in[7], (const float*)d_in[10], (const float*)d_in[13]};
    const float* fcW = (const float*)d_in[14];
    const float* fcb = (const float*)d_in[15];

    // workspace layout
    float* ws    = (float*)d_ws;
    float* hbuf  = ws;                        // N*64
    float* xa    = hbuf + (size_t)N * HID;    // N*64
    float* si    = xa   + (size_t)N * HID;    // N*4
    float* sj    = si   + (size_t)N * HEADS;  // N*4
    float* degf  = sj   + (size_t)N * HEADS;  // N
    int*   degi  = (int*)(degf + N);          // N
    int*   rowptr= degi + N;                  // N+1
    int*   incl  = rowptr + N + 1;            // N
    int*   bsum  = incl + N;                  // 1024
    int*   cursor= bsum + 1024;               // N
    int*   csr   = cursor + N;                // E

    const int nb = (N + 255) / 256;
    const int rng = (N + NXCD - 1) / NXCD;    // dst nodes per XCD-range
    hipMemsetAsync(degi, 0, (size_t)N * sizeof(int), stream);
    k_deg_count<<<(E + 255) / 256, 256, 0, stream>>>(dstp, degi, E);
    k_scan1<<<nb, 256, 0, stream>>>(degi, incl, bsum, N);
    k_scan2<<<1, 64, 0, stream>>>(bsum, nb);
    k_scan3<<<nb, 256, 0, stream>>>(incl, degi, bsum, rowptr, degf, cursor, N, E);
    const int nchunk = (E + 2047) / 2048;
    k_csr_fill_part<<<nchunk * NXCD, 256, 0, stream>>>(srcp, dstp, rowptr, cursor, csr, E, rng);

    const int nblk = (N + 63) / 64;
    const int gblk = (N + 15) / 16;
    const float* cur = x0;
    for (int l = 0; l < 4; ++l) {
        if (l == 0)
            k_linear_t<IN_CH><<<nblk, 256, 0, stream>>>(cur, W[l], B[l], A[l], hbuf, si, sj, N);
        else
            k_linear_t<HID><<<nblk, 256, 0, stream>>>(cur, W[l], B[l], A[l], hbuf, si, sj, N);
        float* ob = (l == 0) ? xa : (float*)cur;   // in-place from layer 1 on
        k_gather<<<gblk, 256, 0, stream>>>(csr, rowptr, hbuf, si, sj, degf, ob, N);
        cur = ob;
    }
    k_fc<<<(N * OUT_SIZE + 255) / 256, 256, 0, stream>>>(cur, fcW, fcb, (float*)d_out, N);
}